// Round 9
// baseline (5709.063 us; speedup 1.0000x reference)
//
#include <hip/hip_runtime.h>
#include <hip/hip_bf16.h>
#include <stdint.h>

typedef unsigned long long u64;
typedef uint32_t u32;
typedef __attribute__((ext_vector_type(8))) short bf16x8;
typedef __attribute__((ext_vector_type(4))) float f32x4;

// RTRBM CD-k step. Exact JAX-threefry; f64 math where sample margins demand it,
// f32/bf16-MFMA fast paths + f64 boundary fixups for the sampling GEMMs.
#define NV 1024
#define NH 512
#define TT 128
#define BB 256
#define TBsz (TT*BB)          // 32768
#define HTBsz (NH*TBsz)       // 16777216
#define VTBsz (NV*TBsz)       // 33554432
#define NWV (NV/64)           // 16
#define NWH (NH/64)           // 8
#define QCAP 1048576u
#define DELTA 5e-4

// ---------------- Threefry-2x32 (JAX exact) ----------------
__host__ __device__ inline void tf2x32(uint32_t k0, uint32_t k1,
                                       uint32_t x0, uint32_t x1,
                                       uint32_t& o0, uint32_t& o1) {
  const uint32_t ks2 = k0 ^ k1 ^ 0x1BD11BDAu;
#define ROTL(x,d) (((x)<<(d))|((x)>>(32-(d))))
#define RND(r) { x0 += x1; x1 = ROTL(x1,r); x1 ^= x0; }
  x0 += k0;  x1 += k1;
  RND(13) RND(15) RND(26) RND(6)
  x0 += k1;  x1 += ks2 + 1u;
  RND(17) RND(29) RND(16) RND(24)
  x0 += ks2; x1 += k0 + 2u;
  RND(13) RND(15) RND(26) RND(6)
  x0 += k0;  x1 += k1 + 3u;
  RND(17) RND(29) RND(16) RND(24)
  x0 += k1;  x1 += ks2 + 4u;
  RND(13) RND(15) RND(26) RND(6)
  x0 += ks2; x1 += k0 + 5u;
  o0 = x0; o1 = x1;
#undef RND
#undef ROTL
}

__device__ inline double tf_uniform64(uint32_t k0, uint32_t k1, uint32_t i) {
  uint32_t o0, o1;
  tf2x32(k0, k1, 0u, i, o0, o1);
  uint32_t bits = o0 ^ o1;
  uint32_t fb = (bits >> 9) | 0x3f800000u;
  float f = __uint_as_float(fb) - 1.0f;
  return (double)f;
}

__device__ inline double sigmoid64(double x) { return 1.0 / (1.0 + exp(-x)); }

// ---------------- f32 -> f64 convert ----------------
__global__ __launch_bounds__(256) void kcvt(const float* __restrict__ s,
                                            double* __restrict__ d, int n) {
  int i = blockIdx.x * 256 + threadIdx.x;
  if (i < n) d[i] = (double)s[i];
}

// ---------------- UB[r4*NH + h] = float4(U[h][4r4..4r4+3]) ----------------------
__global__ __launch_bounds__(256) void kprepU(const float* __restrict__ U,
                                              float4* __restrict__ UB) {
  int i = blockIdx.x * 256 + threadIdx.x;
  int r4 = i / NH;
  int h  = i % NH;
  const float* __restrict__ p = U + (size_t)h*NH + r4*4;
  UB[i] = make_float4(p[0], p[1], p[2], p[3]);
}

// ---------------- UT[r*NH + h] = U[h*NH + r] ------------------------------------
__global__ __launch_bounds__(256) void kprepUT(const float* __restrict__ U,
                                               float* __restrict__ UT) {
  int i = blockIdx.x * 256 + threadIdx.x;
  int r = i / NH;
  int h = i % NH;
  UT[i] = U[(size_t)h*NH + r];
}

// ------- A-fragment prep for kvisM: bf16 pair of W^T in MFMA fragment order -----
// A[pass][vt(64)][ks(16)][lane(64)][i(8)] = bf16_pass(W[h][v]),
// h = ks*32 + (lane>>4)*8 + i, v = vt*16 + (lane&15).
__global__ __launch_bounds__(256) void kprepA(const float* __restrict__ W,
                                              ushort* __restrict__ A1,
                                              ushort* __restrict__ A2) {
  int idx = blockIdx.x * 256 + threadIdx.x;     // 524288 total
  int i    = idx & 7;
  int lane = (idx >> 3) & 63;
  int ks   = (idx >> 9) & 15;
  int vt   = idx >> 13;
  int h = ks*32 + ((lane >> 4) << 3) + i;
  int v = vt*16 + (lane & 15);
  float w = W[(size_t)h*NV + v];
  __hip_bfloat16 b1 = __float2bfloat16(w);
  float r = w - __bfloat162float(b1);
  __hip_bfloat16 b2 = __float2bfloat16(r);
  A1[idx] = *reinterpret_cast<ushort*>(&b1);
  A2[idx] = *reinterpret_cast<ushort*>(&b2);
}

// ---------------- bit-pack v_data: f32 [NV][TBsz] -> u64 [TBsz][NWV] -----------
__global__ __launch_bounds__(256) void kpack_f32(const float* __restrict__ in,
                                                 u64* __restrict__ out) {
  int tb = blockIdx.x * 256 + threadIdx.x;
  for (int w = 0; w < NWV; ++w) {
    u64 m = 0;
    #pragma unroll 8
    for (int j = 0; j < 64; ++j)
      m |= (u64)(in[(size_t)(w*64 + j)*TBsz + tb] != 0.0f ? 1 : 0) << j;
    out[(size_t)tb*NWV + w] = m;
  }
}

// ------- WvT[(t*BB+b)*NH + h] = sum_v W[h,v]*vbit  (f64, t-parallel) -----------
__global__ __launch_bounds__(256) void kWv(const u64* __restrict__ vb,
                                           const double* __restrict__ W64,
                                           double* __restrict__ WvT) {
  const int HM = 8;
  int t  = blockIdx.x / (NH/HM);
  int h0 = (blockIdx.x % (NH/HM)) * HM;
  int tb = t*BB + threadIdx.x;
  u64 m[NWV];
  #pragma unroll
  for (int w = 0; w < NWV; ++w) m[w] = vb[(size_t)tb*NWV + w];
  double acc[HM];
  #pragma unroll
  for (int i = 0; i < HM; ++i) acc[i] = 0.0;
  const double2* __restrict__ W2 = (const double2*)W64;
  for (int w = 0; w < NWV; ++w) {
    u64 mw = m[w];
    #pragma unroll 8
    for (int j2 = 0; j2 < 32; ++j2) {
      double bd0 = (double)((unsigned)((mw >> (2*j2+0)) & 1ull));
      double bd1 = (double)((unsigned)((mw >> (2*j2+1)) & 1ull));
      int vi = w*32 + j2;
      #pragma unroll
      for (int i = 0; i < HM; ++i) {
        double2 wv = W2[(size_t)(h0+i)*(NV/2) + vi];
        acc[i] = fma(bd0, wv.x, acc[i]);
        acc[i] = fma(bd1, wv.y, acc[i]);
      }
    }
  }
  #pragma unroll
  for (int i = 0; i < HM; ++i)
    WvT[(size_t)tb*NH + h0 + i] = acc[i];
}

// ---------------- fused recurrence: 256 blocks x 512 thr, dbuf rA ---------------
// U[h][0:128] cached in registers (loaded once, reused 127 steps); rest from UB.
__global__ __launch_bounds__(512) void krecur(const double* __restrict__ WvT,
                                              const float4* __restrict__ UB,
                                              const float* __restrict__ bh,
                                              const float* __restrict__ binit,
                                              double* __restrict__ rT) {
  __shared__ double rA[2][NH];
  const int b = blockIdx.x;
  const int h = threadIdx.x;
  const double bhd = (double)bh[h];
  float4 ureg[32];
  #pragma unroll
  for (int i = 0; i < 32; ++i) ureg[i] = UB[(size_t)i*NH + h];
  // t = 0
  double p = sigmoid64(WvT[(size_t)b*NH + h] + (double)binit[h]);
  rA[0][h] = p;
  rT[(size_t)b*NH + h] = p;
  __syncthreads();
  int cur = 0;
  for (int t = 1; t < TT; ++t) {
    double acc = WvT[((size_t)t*BB + b)*NH + h];
    double a0=0, a1=0, a2=0, a3=0;
    const double2* __restrict__ rA2 = (const double2*)rA[cur];
    #pragma unroll 8
    for (int r = 0; r < 128; r += 4) {
      float4 u4 = ureg[r >> 2];
      double2 q01 = rA2[(r>>1)+0];
      double2 q23 = rA2[(r>>1)+1];
      a0 = fma((double)u4.x, q01.x, a0);
      a1 = fma((double)u4.y, q01.y, a1);
      a2 = fma((double)u4.z, q23.x, a2);
      a3 = fma((double)u4.w, q23.y, a3);
    }
    #pragma unroll 4
    for (int r = 128; r < NH; r += 4) {
      float4 u4 = UB[(size_t)(r >> 2)*NH + h];
      double2 q01 = rA2[(r>>1)+0];
      double2 q23 = rA2[(r>>1)+1];
      a0 = fma((double)u4.x, q01.x, a0);
      a1 = fma((double)u4.y, q01.y, a1);
      a2 = fma((double)u4.z, q23.x, a2);
      a3 = fma((double)u4.w, q23.y, a3);
    }
    p = sigmoid64((acc + ((a0+a1)+(a2+a3))) + bhd);
    rA[cur ^ 1][h] = p;
    rT[((size_t)t*BB + b)*NH + h] = p;
    __syncthreads();
    cur ^= 1;
  }
}

// ------ transpose rT [t][b][h] f64 -> out_r [h][t][b] f32, fused h1 sampling ----
__global__ __launch_bounds__(256) void ktrans_s(const double* __restrict__ rT,
                                                float* __restrict__ out_r,
                                                uint8_t* __restrict__ hbytes,
                                                u32 k0, u32 k1) {
  __shared__ double lds[32][33];
  int t  = blockIdx.x;
  int h0 = blockIdx.y * 32;
  int b0 = blockIdx.z * 32;
  int tx = threadIdx.x & 31;
  int ty = threadIdx.x >> 5;       // 0..7
  #pragma unroll
  for (int i = 0; i < 4; ++i) {
    int row = ty*4 + i;            // b-row
    lds[row][tx] = rT[((size_t)t*BB + b0 + row)*NH + h0 + tx];
  }
  __syncthreads();
  #pragma unroll
  for (int i = 0; i < 4; ++i) {
    int row = ty*4 + i;            // h-row
    out_r[(size_t)(h0+row)*TBsz + (size_t)t*BB + b0 + tx] = (float)lds[tx][row];
  }
  if (threadIdx.x < 128) {
    int tbr = threadIdx.x >> 2;    // 0..31 (b-rel)
    int bix = threadIdx.x & 3;     // byte index within the 32-h slab
    int tb  = t*BB + b0 + tbr;
    unsigned byte = 0;
    #pragma unroll
    for (int j = 0; j < 8; ++j) {
      int hrel = bix*8 + j;
      double p = lds[tbr][hrel];
      double u = tf_uniform64(k0, k1, (u32)((h0 + hrel)*TBsz + tb));
      byte |= (u < p) ? (1u << j) : 0u;
    }
    hbytes[(size_t)tb*(NH/8) + (h0 >> 3) + bix] = (uint8_t)byte;
  }
}

// ---------------- v-side MFMA fast path (bf16-pair), sigmoid+bernoulli ----------
// O[v][tb] = sum_h W[h][v]*hbit.  A = (Wb1,Wb2) fragments, B = bits->bf16 in LDS.
// Block: 256 thr = 4 waves (2x2), tile 64v x 64tb, K=512.
__global__ __launch_bounds__(256) void kvisM(
    const ushort* __restrict__ A1, const ushort* __restrict__ A2,
    const float* __restrict__ bv, const u64* __restrict__ hbits,
    u64* __restrict__ vbits, float* __restrict__ vf,
    u32* __restrict__ queue, u32* __restrict__ cnt, u32 k0, u32 k1) {
  __shared__ ushort Blds[64*512];              // 64 KB (reused for sbits)
  int nblk = blockIdx.x & 511;                 // TBsz/64 = 512
  int vblk = blockIdx.x >> 9;                  // 0..15
  int tb0 = nblk * 64, v0 = vblk * 64;
  int tid = threadIdx.x;
  // unpack B: 64 cols x 512 k bf16 (0/1), k-block XOR-swizzled by (col&7)
  {
    int c = tid >> 2, seg = tid & 3;
    const u64* hp = hbits + (size_t)(tb0 + c)*NWH + seg*2;
    #pragma unroll
    for (int half = 0; half < 2; ++half) {
      u64 mm = hp[half];
      int kbase = seg*128 + half*64;
      #pragma unroll
      for (int j2 = 0; j2 < 32; ++j2) {
        int k = kbase + 2*j2;
        u32 val = (u32)((mm >> (2*j2)) & 1ull) * 0x3F80u
                | (u32)((mm >> (2*j2+1)) & 1ull) * 0x3F800000u;
        int blk = (k >> 3) ^ (c & 7);
        *(u32*)&Blds[c*512 + (blk << 3) + (k & 7)] = val;
      }
    }
  }
  __syncthreads();
  int wv = tid >> 6, l = tid & 63;
  int wr = wv >> 1, wc = wv & 1;
  f32x4 acc[2][2];
  #pragma unroll
  for (int m = 0; m < 2; ++m)
    #pragma unroll
    for (int n = 0; n < 2; ++n) acc[m][n] = (f32x4){0.f,0.f,0.f,0.f};
  for (int ks = 0; ks < 16; ++ks) {
    bf16x8 bf[2];
    #pragma unroll
    for (int n = 0; n < 2; ++n) {
      int col = wc*32 + n*16 + (l & 15);
      int k = ks*32 + ((l >> 4) << 3);
      int blk = (k >> 3) ^ (col & 7);
      bf[n] = *(const bf16x8*)&Blds[col*512 + (blk << 3)];
    }
    #pragma unroll
    for (int m = 0; m < 2; ++m) {
      int vt = vblk*4 + wr*2 + m;
      size_t abase = (((size_t)vt*16 + ks)*64 + l)*8;
      bf16x8 a1 = *(const bf16x8*)&A1[abase];
      bf16x8 a2 = *(const bf16x8*)&A2[abase];
      #pragma unroll
      for (int n = 0; n < 2; ++n) {
        acc[m][n] = __builtin_amdgcn_mfma_f32_16x16x32_bf16(a1, bf[n], acc[m][n], 0,0,0);
        acc[m][n] = __builtin_amdgcn_mfma_f32_16x16x32_bf16(a2, bf[n], acc[m][n], 0,0,0);
      }
    }
  }
  // epilogue: sample 16 outputs/lane
  u64 mask[2] = {0, 0};
  int coln[2];
  #pragma unroll
  for (int n = 0; n < 2; ++n) {
    int col = wc*32 + n*16 + (l & 15);
    coln[n] = col;
    int tb = tb0 + col;
    #pragma unroll
    for (int m = 0; m < 2; ++m) {
      #pragma unroll
      for (int r = 0; r < 4; ++r) {
        int vrel = wr*32 + m*16 + ((l >> 4) << 2) + r;
        int v = v0 + vrel;
        float p = 1.f / (1.f + __expf(-(acc[m][n][r] + bv[v])));
        size_t o = (size_t)v*TBsz + tb;
        double u = tf_uniform64(k0, k1, (u32)o);
        double diff = (double)p - u;
        unsigned smp = diff > 0.0 ? 1u : 0u;
        if (fabs(diff) < DELTA) {
          u32 s = atomicAdd(cnt, 1u);
          if (s < QCAP) queue[s] = (u32)o;
        }
        if (smp) mask[n] |= 1ull << vrel;
        if (vf) vf[o] = (float)smp;
      }
    }
  }
  if (vbits) {
    __syncthreads();                           // all Blds reads done
    u64* sbits = (u64*)Blds;                   // reuse LDS
    if (tid < 64) sbits[tid] = 0;
    __syncthreads();
    atomicOr(&sbits[coln[0]], mask[0]);
    atomicOr(&sbits[coln[1]], mask[1]);
    __syncthreads();
    if (tid < 64)
      vbits[(size_t)(tb0 + tid)*NWV + (v0 >> 6)] = sbits[tid];
  }
}

// ---------------- v-side exact fixup (f64) --------------------------------------
__global__ __launch_bounds__(256) void kvis_fix(
    const float* __restrict__ W, const float* __restrict__ bv,
    const u64* __restrict__ hbits, u64* __restrict__ fixbits,
    float* __restrict__ vf, const u32* __restrict__ queue,
    const u32* __restrict__ cnt, u32 k0, u32 k1) {
  u32 n = *cnt; if (n > QCAP) n = QCAP;
  for (u32 q = blockIdx.x*256 + threadIdx.x; q < n; q += gridDim.x*256) {
    u32 o = queue[q];
    u32 v = o / TBsz, tb = o % TBsz;
    double a0=0, a1=0, a2=0, a3=0;
    for (int w = 0; w < NWH; ++w) {
      u64 mw = hbits[(size_t)tb*NWH + w];
      for (int j = 0; j < 64; j += 4) {
        if ((mw >> (j+0)) & 1ull) a0 += (double)W[(size_t)(w*64+j+0)*NV + v];
        if ((mw >> (j+1)) & 1ull) a1 += (double)W[(size_t)(w*64+j+1)*NV + v];
        if ((mw >> (j+2)) & 1ull) a2 += (double)W[(size_t)(w*64+j+2)*NV + v];
        if ((mw >> (j+3)) & 1ull) a3 += (double)W[(size_t)(w*64+j+3)*NV + v];
      }
    }
    double p = sigmoid64(((a0+a1)+(a2+a3)) + (double)bv[v]);
    double u = tf_uniform64(k0, k1, o);
    unsigned smp = (u < p) ? 1u : 0u;
    if (vf) vf[o] = (float)smp;
    if (fixbits) {
      size_t wi = (size_t)tb*NWV + (v >> 6);
      unsigned bit = v & 63u;
      unsigned cur = (unsigned)((fixbits[wi] >> bit) & 1ull);
      if (cur != smp) atomicXor(&fixbits[wi], 1ull << bit);
    }
  }
}

// ---------------- h-side fast path (f32): float4 W + transposed-U loads ---------
__global__ __launch_bounds__(256) void khid32(
    const u64* __restrict__ vbits, const float* __restrict__ W,
    const float* __restrict__ UT, const float* __restrict__ bh,
    const float* __restrict__ binit, const float* __restrict__ r32,
    uint8_t* __restrict__ hbytes, u32* __restrict__ queue,
    u32* __restrict__ cnt, u32 k0, u32 k1) {
  const int HM = 8;
  int t  = blockIdx.x / (NH/HM);
  int h0 = (blockIdx.x % (NH/HM)) * HM;
  int tb = t*BB + threadIdx.x;
  u64 m[NWV];
  #pragma unroll
  for (int w = 0; w < NWV; ++w) m[w] = vbits[(size_t)tb*NWV + w];
  float acc[HM];
  #pragma unroll
  for (int i = 0; i < HM; ++i) acc[i] = 0.f;
  const float4* __restrict__ W4 = (const float4*)W;
  for (int w = 0; w < NWV; ++w) {
    u64 mw = m[w];
    #pragma unroll 4
    for (int j4 = 0; j4 < 16; ++j4) {
      float bd0 = (float)((u32)((mw >> (4*j4+0)) & 1ull));
      float bd1 = (float)((u32)((mw >> (4*j4+1)) & 1ull));
      float bd2 = (float)((u32)((mw >> (4*j4+2)) & 1ull));
      float bd3 = (float)((u32)((mw >> (4*j4+3)) & 1ull));
      int vi = w*16 + j4;
      #pragma unroll
      for (int i = 0; i < HM; ++i) {
        float4 wv = W4[(size_t)(h0+i)*(NV/4) + vi];
        acc[i] = fmaf(bd0, wv.x, acc[i]);
        acc[i] = fmaf(bd1, wv.y, acc[i]);
        acc[i] = fmaf(bd2, wv.z, acc[i]);
        acc[i] = fmaf(bd3, wv.w, acc[i]);
      }
    }
  }
  if (t > 0) {
    const float* __restrict__ rp = r32 + (size_t)(t-1)*BB + threadIdx.x;
    const float4* __restrict__ UT4 = (const float4*)UT;
    #pragma unroll 4
    for (int r = 0; r < NH; ++r) {
      float rv = rp[(size_t)r*TBsz];
      float4 ua = UT4[(size_t)r*(NH/4) + (h0 >> 2) + 0];
      float4 ub = UT4[(size_t)r*(NH/4) + (h0 >> 2) + 1];
      acc[0] = fmaf(ua.x, rv, acc[0]);
      acc[1] = fmaf(ua.y, rv, acc[1]);
      acc[2] = fmaf(ua.z, rv, acc[2]);
      acc[3] = fmaf(ua.w, rv, acc[3]);
      acc[4] = fmaf(ub.x, rv, acc[4]);
      acc[5] = fmaf(ub.y, rv, acc[5]);
      acc[6] = fmaf(ub.z, rv, acc[6]);
      acc[7] = fmaf(ub.w, rv, acc[7]);
    }
    #pragma unroll
    for (int i = 0; i < HM; ++i) acc[i] += bh[h0+i];
  } else {
    #pragma unroll
    for (int i = 0; i < HM; ++i) acc[i] += binit[h0+i];
  }
  unsigned byte = 0;
  #pragma unroll
  for (int i = 0; i < HM; ++i) {
    float p = 1.f / (1.f + __expf(-acc[i]));
    size_t o = (size_t)(h0+i)*TBsz + tb;
    double u = tf_uniform64(k0, k1, (u32)o);
    double diff = (double)p - u;
    unsigned smp = diff > 0.0 ? 1u : 0u;
    if (fabs(diff) < DELTA) {
      u32 s = atomicAdd(cnt, 1u);
      if (s < QCAP) queue[s] = (u32)o;
    }
    byte |= smp << i;
  }
  hbytes[(size_t)tb*(NH/8) + (h0 >> 3)] = (uint8_t)byte;
}

// ---------------- h-side exact fixup (f64) --------------------------------------
__global__ __launch_bounds__(256) void khid_fix(
    const u64* __restrict__ vbits, const float* __restrict__ W,
    const double* __restrict__ U64, const float* __restrict__ bh,
    const float* __restrict__ binit, const double* __restrict__ rT,
    u64* __restrict__ fixbits, const u32* __restrict__ queue,
    const u32* __restrict__ cnt, u32 k0, u32 k1) {
  u32 n = *cnt; if (n > QCAP) n = QCAP;
  for (u32 q = blockIdx.x*256 + threadIdx.x; q < n; q += gridDim.x*256) {
    u32 o = queue[q];
    u32 h = o / TBsz, tb = o % TBsz;
    u32 t = tb / BB, b = tb % BB;
    double a0=0, a1=0, a2=0, a3=0;
    for (int w = 0; w < NWV; ++w) {
      u64 mw = vbits[(size_t)tb*NWV + w];
      for (int j = 0; j < 64; j += 4) {
        if ((mw >> (j+0)) & 1ull) a0 += (double)W[(size_t)h*NV + w*64+j+0];
        if ((mw >> (j+1)) & 1ull) a1 += (double)W[(size_t)h*NV + w*64+j+1];
        if ((mw >> (j+2)) & 1ull) a2 += (double)W[(size_t)h*NV + w*64+j+2];
        if ((mw >> (j+3)) & 1ull) a3 += (double)W[(size_t)h*NV + w*64+j+3];
      }
    }
    double logit = (a0+a1) + (a2+a3);
    if (t > 0) {
      const double* __restrict__ rp = rT + ((size_t)(t-1)*BB + b)*NH;
      const double* __restrict__ Ur = U64 + (size_t)h*NH;
      double u0=0, u1=0, u2=0, u3=0;
      for (int r = 0; r < NH; r += 4) {
        u0 = fma(Ur[r+0], rp[r+0], u0);
        u1 = fma(Ur[r+1], rp[r+1], u1);
        u2 = fma(Ur[r+2], rp[r+2], u2);
        u3 = fma(Ur[r+3], rp[r+3], u3);
      }
      logit = (logit + ((u0+u1)+(u2+u3))) + (double)bh[h];
    } else {
      logit += (double)binit[h];
    }
    double p = sigmoid64(logit);
    double u = tf_uniform64(k0, k1, o);
    unsigned smp = (u < p) ? 1u : 0u;
    size_t wi = (size_t)tb*NWH + (h >> 6);
    unsigned bit = h & 63u;
    unsigned cur = (unsigned)((fixbits[wi] >> bit) & 1ull);
    if (cur != smp) atomicXor(&fixbits[wi], 1ull << bit);
  }
}

extern "C" void kernel_launch(void* const* d_in, const int* in_sizes, int n_in,
                              void* d_out, int out_size, void* d_ws, size_t ws_size,
                              hipStream_t stream) {
  const float* vd    = (const float*)d_in[0];
  const float* W     = (const float*)d_in[1];
  const float* U     = (const float*)d_in[2];
  const float* bh    = (const float*)d_in[3];
  const float* binit = (const float*)d_in[4];
  const float* bv    = (const float*)d_in[5];

  float* out_v = (float*)d_out;            // (V,T,B) final samples (written last)
  float* out_r = (float*)d_out + VTBsz;    // (H,T,B) r_data f32
  // WvT (f64, 134.2MB) aliases out_v; dead before final kvisM writes out_v.
  double* WvT = (double*)d_out;

  // ws layout (~168 MB)
  char* w = (char*)d_ws;
  double* rT    = (double*)w;  w += (size_t)HTBsz*8;        // 134.2 MB, [t][b][h]
  u64* vdbits   = (u64*)w;     w += (size_t)TBsz*NWV*8;     // 4 MB
  u64* v1bits   = (u64*)w;     w += (size_t)TBsz*NWV*8;     // 4 MB
  u64* h1bits   = (u64*)w;     w += (size_t)TBsz*NWH*8;     // 2 MB
  u64* h2bits   = (u64*)w;     w += (size_t)TBsz*NWH*8;     // 2 MB
  double* W64   = (double*)w;  w += (size_t)NH*NV*8;        // 4 MB
  double* U64   = (double*)w;  w += (size_t)NH*NH*8;        // 2 MB
  float4* UB    = (float4*)w;  w += (size_t)NH*NH*4;        // 1 MB
  float* UT     = (float*)w;   w += (size_t)NH*NH*4;        // 1 MB
  ushort* A1    = (ushort*)w;  w += (size_t)NH*NV*2;        // 1 MB (Wb1 frags)
  ushort* A2    = (ushort*)w;  w += (size_t)NH*NV*2;        // 1 MB (Wb2 frags)
  u32* q0       = (u32*)w;     w += (size_t)QCAP*4;         // 4 MB
  u32* q1       = (u32*)w;     w += (size_t)QCAP*4;         // 4 MB
  u32* q2       = (u32*)w;     w += (size_t)QCAP*4;         // 4 MB
  u32* cnt      = (u32*)w;     w += 256;
  (void)ws_size; (void)in_sizes; (void)n_in; (void)out_size;

  // host-side key derivation (jax.random.key(42), partitionable threefry splits)
  uint32_t ka0,ka1, sk0,sk1;
  tf2x32(0u,42u, 0u,0u, ka0,ka1);
  tf2x32(0u,42u, 0u,1u, sk0,sk1);
  uint32_t kb0,kb1, k10,k11, k20,k21;
  tf2x32(ka0,ka1, 0u,0u, kb0,kb1);
  tf2x32(ka0,ka1, 0u,1u, k10,k11);
  tf2x32(ka0,ka1, 0u,2u, k20,k21);
  uint32_t kc0,kc1, kf0,kf1;
  tf2x32(kb0,kb1, 0u,0u, kc0,kc1);
  tf2x32(kb0,kb1, 0u,1u, kf0,kf1);

  hipMemsetAsync(cnt, 0, 3*sizeof(u32), stream);

  // 0) preps
  kcvt<<<(NH*NV+255)/256, 256, 0, stream>>>(W, W64, NH*NV);
  kcvt<<<(NH*NH+255)/256, 256, 0, stream>>>(U, U64, NH*NH);
  kprepU<<<(NH*NH/4)/256, 256, 0, stream>>>(U, UB);
  kprepUT<<<(NH*NH)/256, 256, 0, stream>>>(U, UT);
  kprepA<<<(NH*NV)/256, 256, 0, stream>>>(W, A1, A2);
  kpack_f32<<<TBsz/256, 256, 0, stream>>>(vd, vdbits);

  // 1) WvT = (W @ v_data)^T  (f64, [t][b][h])
  kWv<<<TT*(NH/8), 256, 0, stream>>>(vdbits, W64, WvT);

  // 2) fused mean-field recurrence
  krecur<<<BB, NH, 0, stream>>>(WvT, UB, bh, binit, rT);

  // 2b) out_r transpose + h1 = bernoulli(sk, r) fused
  ktrans_s<<<dim3(TT, NH/32, BB/32), 256, 0, stream>>>(rT, out_r,
                                                       (uint8_t*)h1bits, sk0, sk1);

  // 3) v1 = bernoulli(k1, sigmoid(W^T h1 + bv)) : bf16-MFMA fast + f64 fix
  kvisM<<<16*512, 256, 0, stream>>>(A1, A2, bv, h1bits, v1bits, nullptr,
                                    q0, cnt+0, k10, k11);
  kvis_fix<<<128, 256, 0, stream>>>(W, bv, h1bits, v1bits, nullptr,
                                    q0, cnt+0, k10, k11);

  // 4) h2 = bernoulli(k2, sigmoid(W v1 + U r_lag + bias)) : f32 fast + f64 fix
  khid32<<<TT*(NH/8), 256, 0, stream>>>(v1bits, W, UT, bh, binit, out_r,
                                        (uint8_t*)h2bits, q1, cnt+1, k20, k21);
  khid_fix<<<128, 256, 0, stream>>>(v1bits, W, U64, bh, binit, rT,
                                    h2bits, q1, cnt+1, k20, k21);

  // 5) v_model = bernoulli(kf, sigmoid(W^T h2 + bv)) -> out_v
  kvisM<<<16*512, 256, 0, stream>>>(A1, A2, bv, h2bits, nullptr, out_v,
                                    q2, cnt+2, kf0, kf1);
  kvis_fix<<<128, 256, 0, stream>>>(W, bv, h2bits, nullptr, out_v,
                                    q2, cnt+2, kf0, kf1);
}

// Round 10
// 5023.284 us; speedup vs baseline: 1.1365x; 1.1365x over previous
//
#include <hip/hip_runtime.h>
#include <hip/hip_bf16.h>
#include <stdint.h>

typedef unsigned long long u64;
typedef uint32_t u32;
typedef __attribute__((ext_vector_type(8))) short bf16x8;
typedef __attribute__((ext_vector_type(4))) float f32x4;

// RTRBM CD-k step. Exact JAX-threefry; f64 where sample margins demand it;
// bf16-pair MFMA fast paths + f64 boundary fixups for all sampling GEMMs.
#define NV 1024
#define NH 512
#define TT 128
#define BB 256
#define TBsz (TT*BB)          // 32768
#define HTBsz (NH*TBsz)       // 16777216
#define VTBsz (NV*TBsz)       // 33554432
#define NWV (NV/64)           // 16
#define NWH (NH/64)           // 8
#define QCAP 1048576u
#define DELTA 5e-4

// ---------------- Threefry-2x32 (JAX exact) ----------------
__host__ __device__ inline void tf2x32(uint32_t k0, uint32_t k1,
                                       uint32_t x0, uint32_t x1,
                                       uint32_t& o0, uint32_t& o1) {
  const uint32_t ks2 = k0 ^ k1 ^ 0x1BD11BDAu;
#define ROTL(x,d) (((x)<<(d))|((x)>>(32-(d))))
#define RND(r) { x0 += x1; x1 = ROTL(x1,r); x1 ^= x0; }
  x0 += k0;  x1 += k1;
  RND(13) RND(15) RND(26) RND(6)
  x0 += k1;  x1 += ks2 + 1u;
  RND(17) RND(29) RND(16) RND(24)
  x0 += ks2; x1 += k0 + 2u;
  RND(13) RND(15) RND(26) RND(6)
  x0 += k0;  x1 += k1 + 3u;
  RND(17) RND(29) RND(16) RND(24)
  x0 += k1;  x1 += ks2 + 4u;
  RND(13) RND(15) RND(26) RND(6)
  x0 += ks2; x1 += k0 + 5u;
  o0 = x0; o1 = x1;
#undef RND
#undef ROTL
}

__device__ inline double tf_uniform64(uint32_t k0, uint32_t k1, uint32_t i) {
  uint32_t o0, o1;
  tf2x32(k0, k1, 0u, i, o0, o1);
  uint32_t bits = o0 ^ o1;
  uint32_t fb = (bits >> 9) | 0x3f800000u;
  float f = __uint_as_float(fb) - 1.0f;
  return (double)f;
}

__device__ inline double sigmoid64(double x) { return 1.0 / (1.0 + exp(-x)); }

// ---------------- f32 -> f64 convert ----------------
__global__ __launch_bounds__(256) void kcvt(const float* __restrict__ s,
                                            double* __restrict__ d, int n) {
  int i = blockIdx.x * 256 + threadIdx.x;
  if (i < n) d[i] = (double)s[i];
}

// ---------------- UB[r4*NH + h] = float4(U[h][4r4..4r4+3]) ----------------------
__global__ __launch_bounds__(256) void kprepU(const float* __restrict__ U,
                                              float4* __restrict__ UB) {
  int i = blockIdx.x * 256 + threadIdx.x;
  int r4 = i / NH;
  int h  = i % NH;
  const float* __restrict__ p = U + (size_t)h*NH + r4*4;
  UB[i] = make_float4(p[0], p[1], p[2], p[3]);
}

// ------- A-fragments for kvisM: bf16 pair of W^T (row=v, k=h) -------------------
__global__ __launch_bounds__(256) void kprepA(const float* __restrict__ W,
                                              ushort* __restrict__ A1,
                                              ushort* __restrict__ A2) {
  int idx = blockIdx.x * 256 + threadIdx.x;     // 524288
  int i    = idx & 7;
  int lane = (idx >> 3) & 63;
  int ks   = (idx >> 9) & 15;
  int vt   = idx >> 13;
  int h = ks*32 + ((lane >> 4) << 3) + i;
  int v = vt*16 + (lane & 15);
  float w = W[(size_t)h*NV + v];
  __hip_bfloat16 b1 = __float2bfloat16(w);
  float r = w - __bfloat162float(b1);
  __hip_bfloat16 b2 = __float2bfloat16(r);
  A1[idx] = *reinterpret_cast<ushort*>(&b1);
  A2[idx] = *reinterpret_cast<ushort*>(&b2);
}

// ------- A-fragments for khidM: W (row=h, k=v) ----------------------------------
__global__ __launch_bounds__(256) void kprepAW(const float* __restrict__ W,
                                               ushort* __restrict__ AW1,
                                               ushort* __restrict__ AW2) {
  int idx = blockIdx.x * 256 + threadIdx.x;     // 524288
  int i    = idx & 7;
  int lane = (idx >> 3) & 63;
  int kt   = (idx >> 9) & 31;
  int ht   = idx >> 14;
  int h = ht*16 + (lane & 15);
  int v = kt*32 + ((lane >> 4) << 3) + i;
  float w = W[(size_t)h*NV + v];
  __hip_bfloat16 b1 = __float2bfloat16(w);
  float r = w - __bfloat162float(b1);
  __hip_bfloat16 b2 = __float2bfloat16(r);
  AW1[idx] = *reinterpret_cast<ushort*>(&b1);
  AW2[idx] = *reinterpret_cast<ushort*>(&b2);
}

// ------- A-fragments for khidM: U (row=h, k=r) ----------------------------------
__global__ __launch_bounds__(256) void kprepAU(const float* __restrict__ U,
                                               ushort* __restrict__ AU1,
                                               ushort* __restrict__ AU2) {
  int idx = blockIdx.x * 256 + threadIdx.x;     // 262144
  int i    = idx & 7;
  int lane = (idx >> 3) & 63;
  int kt   = (idx >> 9) & 15;
  int ht   = idx >> 13;
  int h = ht*16 + (lane & 15);
  int r = kt*32 + ((lane >> 4) << 3) + i;
  float u = U[(size_t)h*NH + r];
  __hip_bfloat16 b1 = __float2bfloat16(u);
  float rs = u - __bfloat162float(b1);
  __hip_bfloat16 b2 = __float2bfloat16(rs);
  AU1[idx] = *reinterpret_cast<ushort*>(&b1);
  AU2[idx] = *reinterpret_cast<ushort*>(&b2);
}

// ---------------- bit-pack v_data: f32 [NV][TBsz] -> u64 [TBsz][NWV] -----------
__global__ __launch_bounds__(256) void kpack_f32(const float* __restrict__ in,
                                                 u64* __restrict__ out) {
  int tb = blockIdx.x * 256 + threadIdx.x;
  for (int w = 0; w < NWV; ++w) {
    u64 m = 0;
    #pragma unroll 8
    for (int j = 0; j < 64; ++j)
      m |= (u64)(in[(size_t)(w*64 + j)*TBsz + tb] != 0.0f ? 1 : 0) << j;
    out[(size_t)tb*NWV + w] = m;
  }
}

// ------- WvT[(t*BB+b)*NH + h] = sum_v W[h,v]*vbit  (f64, t-parallel) -----------
__global__ __launch_bounds__(256) void kWv(const u64* __restrict__ vb,
                                           const double* __restrict__ W64,
                                           double* __restrict__ WvT) {
  const int HM = 8;
  int t  = blockIdx.x / (NH/HM);
  int h0 = (blockIdx.x % (NH/HM)) * HM;
  int tb = t*BB + threadIdx.x;
  u64 m[NWV];
  #pragma unroll
  for (int w = 0; w < NWV; ++w) m[w] = vb[(size_t)tb*NWV + w];
  double acc[HM];
  #pragma unroll
  for (int i = 0; i < HM; ++i) acc[i] = 0.0;
  const double2* __restrict__ W2 = (const double2*)W64;
  for (int w = 0; w < NWV; ++w) {
    u64 mw = m[w];
    #pragma unroll 8
    for (int j2 = 0; j2 < 32; ++j2) {
      double bd0 = (double)((unsigned)((mw >> (2*j2+0)) & 1ull));
      double bd1 = (double)((unsigned)((mw >> (2*j2+1)) & 1ull));
      int vi = w*32 + j2;
      #pragma unroll
      for (int i = 0; i < HM; ++i) {
        double2 wv = W2[(size_t)(h0+i)*(NV/2) + vi];
        acc[i] = fma(bd0, wv.x, acc[i]);
        acc[i] = fma(bd1, wv.y, acc[i]);
      }
    }
  }
  #pragma unroll
  for (int i = 0; i < HM; ++i)
    WvT[(size_t)tb*NH + h0 + i] = acc[i];
}

// ---------------- fused recurrence (R8-proven): 256 blocks x 512 thr ------------
__global__ __launch_bounds__(512) void krecur(const double* __restrict__ WvT,
                                              const float4* __restrict__ UB,
                                              const float* __restrict__ bh,
                                              const float* __restrict__ binit,
                                              double* __restrict__ rT) {
  __shared__ double rA[2][NH];
  const int b = blockIdx.x;
  const int h = threadIdx.x;
  const double bhd = (double)bh[h];
  double p = sigmoid64(WvT[(size_t)b*NH + h] + (double)binit[h]);
  rA[0][h] = p;
  rT[(size_t)b*NH + h] = p;
  __syncthreads();
  int cur = 0;
  for (int t = 1; t < TT; ++t) {
    double acc = WvT[((size_t)t*BB + b)*NH + h];
    double a0=0, a1=0, a2=0, a3=0;
    const double2* __restrict__ rA2 = (const double2*)rA[cur];
    #pragma unroll 4
    for (int r = 0; r < NH; r += 4) {
      float4 u4 = UB[(size_t)(r >> 2)*NH + h];
      double2 q01 = rA2[(r>>1)+0];
      double2 q23 = rA2[(r>>1)+1];
      a0 = fma((double)u4.x, q01.x, a0);
      a1 = fma((double)u4.y, q01.y, a1);
      a2 = fma((double)u4.z, q23.x, a2);
      a3 = fma((double)u4.w, q23.y, a3);
    }
    p = sigmoid64((acc + ((a0+a1)+(a2+a3))) + bhd);
    rA[cur ^ 1][h] = p;
    rT[((size_t)t*BB + b)*NH + h] = p;
    __syncthreads();
    cur ^= 1;
  }
}

// ------ transpose rT -> out_r f32, fused h1 = bernoulli(sk, r) ------------------
__global__ __launch_bounds__(256) void ktrans_s(const double* __restrict__ rT,
                                                float* __restrict__ out_r,
                                                uint8_t* __restrict__ hbytes,
                                                u32 k0, u32 k1) {
  __shared__ double lds[32][33];
  int t  = blockIdx.x;
  int h0 = blockIdx.y * 32;
  int b0 = blockIdx.z * 32;
  int tx = threadIdx.x & 31;
  int ty = threadIdx.x >> 5;
  #pragma unroll
  for (int i = 0; i < 4; ++i) {
    int row = ty*4 + i;
    lds[row][tx] = rT[((size_t)t*BB + b0 + row)*NH + h0 + tx];
  }
  __syncthreads();
  #pragma unroll
  for (int i = 0; i < 4; ++i) {
    int row = ty*4 + i;
    out_r[(size_t)(h0+row)*TBsz + (size_t)t*BB + b0 + tx] = (float)lds[tx][row];
  }
  if (threadIdx.x < 128) {
    int tbr = threadIdx.x >> 2;
    int bix = threadIdx.x & 3;
    int tb  = t*BB + b0 + tbr;
    unsigned byte = 0;
    #pragma unroll
    for (int j = 0; j < 8; ++j) {
      int hrel = bix*8 + j;
      double p = lds[tbr][hrel];
      double u = tf_uniform64(k0, k1, (u32)((h0 + hrel)*TBsz + tb));
      byte |= (u < p) ? (1u << j) : 0u;
    }
    hbytes[(size_t)tb*(NH/8) + (h0 >> 3) + bix] = (uint8_t)byte;
  }
}

// ---------------- v-side MFMA (validated R9): O[v][tb] = W^T hbits --------------
__global__ __launch_bounds__(256) void kvisM(
    const ushort* __restrict__ A1, const ushort* __restrict__ A2,
    const float* __restrict__ bv, const u64* __restrict__ hbits,
    u64* __restrict__ vbits, float* __restrict__ vf,
    u32* __restrict__ queue, u32* __restrict__ cnt, u32 k0, u32 k1) {
  __shared__ ushort Blds[64*512];
  int nblk = blockIdx.x & 511;
  int vblk = blockIdx.x >> 9;
  int tb0 = nblk * 64, v0 = vblk * 64;
  int tid = threadIdx.x;
  {
    int c = tid >> 2, seg = tid & 3;
    const u64* hp = hbits + (size_t)(tb0 + c)*NWH + seg*2;
    #pragma unroll
    for (int half = 0; half < 2; ++half) {
      u64 mm = hp[half];
      int kbase = seg*128 + half*64;
      #pragma unroll
      for (int j2 = 0; j2 < 32; ++j2) {
        int k = kbase + 2*j2;
        u32 val = (u32)((mm >> (2*j2)) & 1ull) * 0x3F80u
                | (u32)((mm >> (2*j2+1)) & 1ull) * 0x3F800000u;
        int blk = (k >> 3) ^ (c & 7);
        *(u32*)&Blds[c*512 + (blk << 3) + (k & 7)] = val;
      }
    }
  }
  __syncthreads();
  int wv = tid >> 6, l = tid & 63;
  int wr = wv >> 1, wc = wv & 1;
  f32x4 acc[2][2];
  #pragma unroll
  for (int m = 0; m < 2; ++m)
    #pragma unroll
    for (int n = 0; n < 2; ++n) acc[m][n] = (f32x4){0.f,0.f,0.f,0.f};
  for (int ks = 0; ks < 16; ++ks) {
    bf16x8 bf[2];
    #pragma unroll
    for (int n = 0; n < 2; ++n) {
      int col = wc*32 + n*16 + (l & 15);
      int k = ks*32 + ((l >> 4) << 3);
      int blk = (k >> 3) ^ (col & 7);
      bf[n] = *(const bf16x8*)&Blds[col*512 + (blk << 3)];
    }
    #pragma unroll
    for (int m = 0; m < 2; ++m) {
      int vt = vblk*4 + wr*2 + m;
      size_t abase = (((size_t)vt*16 + ks)*64 + l)*8;
      bf16x8 a1 = *(const bf16x8*)&A1[abase];
      bf16x8 a2 = *(const bf16x8*)&A2[abase];
      #pragma unroll
      for (int n = 0; n < 2; ++n) {
        acc[m][n] = __builtin_amdgcn_mfma_f32_16x16x32_bf16(a1, bf[n], acc[m][n], 0,0,0);
        acc[m][n] = __builtin_amdgcn_mfma_f32_16x16x32_bf16(a2, bf[n], acc[m][n], 0,0,0);
      }
    }
  }
  u64 mask[2] = {0, 0};
  int coln[2];
  #pragma unroll
  for (int n = 0; n < 2; ++n) {
    int col = wc*32 + n*16 + (l & 15);
    coln[n] = col;
    int tb = tb0 + col;
    #pragma unroll
    for (int m = 0; m < 2; ++m) {
      #pragma unroll
      for (int r = 0; r < 4; ++r) {
        int vrel = wr*32 + m*16 + ((l >> 4) << 2) + r;
        int v = v0 + vrel;
        float p = 1.f / (1.f + __expf(-(acc[m][n][r] + bv[v])));
        size_t o = (size_t)v*TBsz + tb;
        double u = tf_uniform64(k0, k1, (u32)o);
        double diff = (double)p - u;
        unsigned smp = diff > 0.0 ? 1u : 0u;
        if (fabs(diff) < DELTA) {
          u32 s = atomicAdd(cnt, 1u);
          if (s < QCAP) queue[s] = (u32)o;
        }
        if (smp) mask[n] |= 1ull << vrel;
        if (vf) vf[o] = (float)smp;
      }
    }
  }
  if (vbits) {
    __syncthreads();
    u64* sbits = (u64*)Blds;
    if (tid < 64) sbits[tid] = 0;
    __syncthreads();
    atomicOr(&sbits[coln[0]], mask[0]);
    atomicOr(&sbits[coln[1]], mask[1]);
    __syncthreads();
    if (tid < 64)
      vbits[(size_t)(tb0 + tid)*NWV + (v0 >> 6)] = sbits[tid];
  }
}

// ---------------- h-side MFMA: O[h][tb] = W@v1 + U@r_lag ------------------------
// 4 phases: v-bits k=0..511, 512..1023; r-plane1, r-plane2 (skipped at t=0).
__global__ __launch_bounds__(256) void khidM(
    const ushort* __restrict__ AW1, const ushort* __restrict__ AW2,
    const ushort* __restrict__ AU1, const ushort* __restrict__ AU2,
    const float* __restrict__ bh, const float* __restrict__ binit,
    const u64* __restrict__ vbits, const float* __restrict__ r32,
    u64* __restrict__ h2bits, u32* __restrict__ queue,
    u32* __restrict__ cnt, u32 k0, u32 k1) {
  __shared__ ushort Blds[64*512];
  int nblk = blockIdx.x & 511;
  int hblk = blockIdx.x >> 9;                  // 0..7
  int tb0 = nblk * 64, h0 = hblk * 64;
  int t = tb0 >> 8;
  int tid = threadIdx.x;
  int wv = tid >> 6, l = tid & 63;
  int wr = wv >> 1, wc = wv & 1;
  f32x4 acc[2][2];
  #pragma unroll
  for (int m = 0; m < 2; ++m)
    #pragma unroll
    for (int n = 0; n < 2; ++n) acc[m][n] = (f32x4){0.f,0.f,0.f,0.f};

  // ---- V phases (W @ v1bits), K chunks q=0,1
  for (int q = 0; q < 2; ++q) {
    {
      int c = tid >> 2, seg = tid & 3;
      const u64* vp = vbits + (size_t)(tb0 + c)*NWV + q*8 + seg*2;
      #pragma unroll
      for (int half = 0; half < 2; ++half) {
        u64 mm = vp[half];
        int kbase = seg*128 + half*64;
        #pragma unroll
        for (int j2 = 0; j2 < 32; ++j2) {
          int k = kbase + 2*j2;
          u32 val = (u32)((mm >> (2*j2)) & 1ull) * 0x3F80u
                  | (u32)((mm >> (2*j2+1)) & 1ull) * 0x3F800000u;
          int blk = (k >> 3) ^ (c & 7);
          *(u32*)&Blds[c*512 + (blk << 3) + (k & 7)] = val;
        }
      }
    }
    __syncthreads();
    for (int ks = 0; ks < 16; ++ks) {
      int kt = q*16 + ks;
      bf16x8 bf[2];
      #pragma unroll
      for (int n = 0; n < 2; ++n) {
        int col = wc*32 + n*16 + (l & 15);
        int k = ks*32 + ((l >> 4) << 3);
        int blk = (k >> 3) ^ (col & 7);
        bf[n] = *(const bf16x8*)&Blds[col*512 + (blk << 3)];
      }
      #pragma unroll
      for (int m = 0; m < 2; ++m) {
        int ht = hblk*4 + wr*2 + m;
        size_t abase = (((size_t)ht*32 + kt)*64 + l)*8;
        bf16x8 a1 = *(const bf16x8*)&AW1[abase];
        bf16x8 a2 = *(const bf16x8*)&AW2[abase];
        #pragma unroll
        for (int n = 0; n < 2; ++n) {
          acc[m][n] = __builtin_amdgcn_mfma_f32_16x16x32_bf16(a1, bf[n], acc[m][n], 0,0,0);
          acc[m][n] = __builtin_amdgcn_mfma_f32_16x16x32_bf16(a2, bf[n], acc[m][n], 0,0,0);
        }
      }
    }
    __syncthreads();
  }

  // ---- R phases (U @ r_lag), bf16 planes pl=0,1
  if (t > 0) {
    int tbl0 = tb0 - 256;                      // lagged tb base
    for (int pl = 0; pl < 2; ++pl) {
      {
        int c = tid >> 2, rseg = tid & 3;
        const float* rp = r32 + tbl0 + c;
        for (int rr = 0; rr < 128; ++rr) {
          int r = rseg*128 + rr;
          float x = rp[(size_t)r*TBsz];
          __hip_bfloat16 b1 = __float2bfloat16(x);
          ushort ub;
          if (pl == 0) {
            ub = *reinterpret_cast<ushort*>(&b1);
          } else {
            float res = x - __bfloat162float(b1);
            __hip_bfloat16 b2 = __float2bfloat16(res);
            ub = *reinterpret_cast<ushort*>(&b2);
          }
          int blk = (r >> 3) ^ (c & 7);
          Blds[c*512 + (blk << 3) + (r & 7)] = ub;
        }
      }
      __syncthreads();
      for (int ks = 0; ks < 16; ++ks) {
        bf16x8 bf[2];
        #pragma unroll
        for (int n = 0; n < 2; ++n) {
          int col = wc*32 + n*16 + (l & 15);
          int k = ks*32 + ((l >> 4) << 3);
          int blk = (k >> 3) ^ (col & 7);
          bf[n] = *(const bf16x8*)&Blds[col*512 + (blk << 3)];
        }
        #pragma unroll
        for (int m = 0; m < 2; ++m) {
          int ht = hblk*4 + wr*2 + m;
          size_t abase = (((size_t)ht*16 + ks)*64 + l)*8;
          bf16x8 a1 = *(const bf16x8*)&AU1[abase];
          bf16x8 a2 = *(const bf16x8*)&AU2[abase];
          #pragma unroll
          for (int n = 0; n < 2; ++n) {
            acc[m][n] = __builtin_amdgcn_mfma_f32_16x16x32_bf16(a1, bf[n], acc[m][n], 0,0,0);
            acc[m][n] = __builtin_amdgcn_mfma_f32_16x16x32_bf16(a2, bf[n], acc[m][n], 0,0,0);
          }
        }
      }
      __syncthreads();
    }
  }

  // ---- epilogue: sigmoid + threefry bernoulli + queue + bit-pack
  const float* __restrict__ bias = (t > 0) ? bh : binit;
  u64 mask[2] = {0, 0};
  int coln[2];
  #pragma unroll
  for (int n = 0; n < 2; ++n) {
    int col = wc*32 + n*16 + (l & 15);
    coln[n] = col;
    int tb = tb0 + col;
    #pragma unroll
    for (int m = 0; m < 2; ++m) {
      #pragma unroll
      for (int r = 0; r < 4; ++r) {
        int hrel = wr*32 + m*16 + ((l >> 4) << 2) + r;
        int h = h0 + hrel;
        float p = 1.f / (1.f + __expf(-(acc[m][n][r] + bias[h])));
        size_t o = (size_t)h*TBsz + tb;
        double u = tf_uniform64(k0, k1, (u32)o);
        double diff = (double)p - u;
        unsigned smp = diff > 0.0 ? 1u : 0u;
        if (fabs(diff) < DELTA) {
          u32 s = atomicAdd(cnt, 1u);
          if (s < QCAP) queue[s] = (u32)o;
        }
        if (smp) mask[n] |= 1ull << hrel;
      }
    }
  }
  __syncthreads();
  u64* sbits = (u64*)Blds;
  if (tid < 64) sbits[tid] = 0;
  __syncthreads();
  atomicOr(&sbits[coln[0]], mask[0]);
  atomicOr(&sbits[coln[1]], mask[1]);
  __syncthreads();
  if (tid < 64)
    h2bits[(size_t)(tb0 + tid)*NWH + hblk] = sbits[tid];
}

// ---------------- v-side exact fixup (f64) --------------------------------------
__global__ __launch_bounds__(256) void kvis_fix(
    const float* __restrict__ W, const float* __restrict__ bv,
    const u64* __restrict__ hbits, u64* __restrict__ fixbits,
    float* __restrict__ vf, const u32* __restrict__ queue,
    const u32* __restrict__ cnt, u32 k0, u32 k1) {
  u32 n = *cnt; if (n > QCAP) n = QCAP;
  for (u32 q = blockIdx.x*256 + threadIdx.x; q < n; q += gridDim.x*256) {
    u32 o = queue[q];
    u32 v = o / TBsz, tb = o % TBsz;
    double a0=0, a1=0, a2=0, a3=0;
    for (int w = 0; w < NWH; ++w) {
      u64 mw = hbits[(size_t)tb*NWH + w];
      for (int j = 0; j < 64; j += 4) {
        if ((mw >> (j+0)) & 1ull) a0 += (double)W[(size_t)(w*64+j+0)*NV + v];
        if ((mw >> (j+1)) & 1ull) a1 += (double)W[(size_t)(w*64+j+1)*NV + v];
        if ((mw >> (j+2)) & 1ull) a2 += (double)W[(size_t)(w*64+j+2)*NV + v];
        if ((mw >> (j+3)) & 1ull) a3 += (double)W[(size_t)(w*64+j+3)*NV + v];
      }
    }
    double p = sigmoid64(((a0+a1)+(a2+a3)) + (double)bv[v]);
    double u = tf_uniform64(k0, k1, o);
    unsigned smp = (u < p) ? 1u : 0u;
    if (vf) vf[o] = (float)smp;
    if (fixbits) {
      size_t wi = (size_t)tb*NWV + (v >> 6);
      unsigned bit = v & 63u;
      unsigned cur = (unsigned)((fixbits[wi] >> bit) & 1ull);
      if (cur != smp) atomicXor(&fixbits[wi], 1ull << bit);
    }
  }
}

// ---------------- h-side exact fixup (f64) --------------------------------------
__global__ __launch_bounds__(256) void khid_fix(
    const u64* __restrict__ vbits, const float* __restrict__ W,
    const double* __restrict__ U64, const float* __restrict__ bh,
    const float* __restrict__ binit, const double* __restrict__ rT,
    u64* __restrict__ fixbits, const u32* __restrict__ queue,
    const u32* __restrict__ cnt, u32 k0, u32 k1) {
  u32 n = *cnt; if (n > QCAP) n = QCAP;
  for (u32 q = blockIdx.x*256 + threadIdx.x; q < n; q += gridDim.x*256) {
    u32 o = queue[q];
    u32 h = o / TBsz, tb = o % TBsz;
    u32 t = tb / BB, b = tb % BB;
    double a0=0, a1=0, a2=0, a3=0;
    for (int w = 0; w < NWV; ++w) {
      u64 mw = vbits[(size_t)tb*NWV + w];
      for (int j = 0; j < 64; j += 4) {
        if ((mw >> (j+0)) & 1ull) a0 += (double)W[(size_t)h*NV + w*64+j+0];
        if ((mw >> (j+1)) & 1ull) a1 += (double)W[(size_t)h*NV + w*64+j+1];
        if ((mw >> (j+2)) & 1ull) a2 += (double)W[(size_t)h*NV + w*64+j+2];
        if ((mw >> (j+3)) & 1ull) a3 += (double)W[(size_t)h*NV + w*64+j+3];
      }
    }
    double logit = (a0+a1) + (a2+a3);
    if (t > 0) {
      const double* __restrict__ rp = rT + ((size_t)(t-1)*BB + b)*NH;
      const double* __restrict__ Ur = U64 + (size_t)h*NH;
      double u0=0, u1=0, u2=0, u3=0;
      for (int r = 0; r < NH; r += 4) {
        u0 = fma(Ur[r+0], rp[r+0], u0);
        u1 = fma(Ur[r+1], rp[r+1], u1);
        u2 = fma(Ur[r+2], rp[r+2], u2);
        u3 = fma(Ur[r+3], rp[r+3], u3);
      }
      logit = (logit + ((u0+u1)+(u2+u3))) + (double)bh[h];
    } else {
      logit += (double)binit[h];
    }
    double p = sigmoid64(logit);
    double u = tf_uniform64(k0, k1, o);
    unsigned smp = (u < p) ? 1u : 0u;
    size_t wi = (size_t)tb*NWH + (h >> 6);
    unsigned bit = h & 63u;
    unsigned cur = (unsigned)((fixbits[wi] >> bit) & 1ull);
    if (cur != smp) atomicXor(&fixbits[wi], 1ull << bit);
  }
}

extern "C" void kernel_launch(void* const* d_in, const int* in_sizes, int n_in,
                              void* d_out, int out_size, void* d_ws, size_t ws_size,
                              hipStream_t stream) {
  const float* vd    = (const float*)d_in[0];
  const float* W     = (const float*)d_in[1];
  const float* U     = (const float*)d_in[2];
  const float* bh    = (const float*)d_in[3];
  const float* binit = (const float*)d_in[4];
  const float* bv    = (const float*)d_in[5];

  float* out_v = (float*)d_out;            // (V,T,B) final samples (written last)
  float* out_r = (float*)d_out + VTBsz;    // (H,T,B) r_data f32
  double* WvT = (double*)d_out;            // aliases out_v region; dead by final kvisM

  // ws layout (~171 MB)
  char* w = (char*)d_ws;
  double* rT    = (double*)w;  w += (size_t)HTBsz*8;        // 134.2 MB, [t][b][h]
  u64* vdbits   = (u64*)w;     w += (size_t)TBsz*NWV*8;     // 4 MB
  u64* v1bits   = (u64*)w;     w += (size_t)TBsz*NWV*8;     // 4 MB
  u64* h1bits   = (u64*)w;     w += (size_t)TBsz*NWH*8;     // 2 MB
  u64* h2bits   = (u64*)w;     w += (size_t)TBsz*NWH*8;     // 2 MB
  double* W64   = (double*)w;  w += (size_t)NH*NV*8;        // 4 MB
  double* U64   = (double*)w;  w += (size_t)NH*NH*8;        // 2 MB
  float4* UB    = (float4*)w;  w += (size_t)NH*NH*4;        // 1 MB
  ushort* A1    = (ushort*)w;  w += (size_t)NH*NV*2;        // 1 MB
  ushort* A2    = (ushort*)w;  w += (size_t)NH*NV*2;        // 1 MB
  ushort* AW1   = (ushort*)w;  w += (size_t)NH*NV*2;        // 1 MB
  ushort* AW2   = (ushort*)w;  w += (size_t)NH*NV*2;        // 1 MB
  ushort* AU1   = (ushort*)w;  w += (size_t)NH*NH*2;        // 0.5 MB
  ushort* AU2   = (ushort*)w;  w += (size_t)NH*NH*2;        // 0.5 MB
  u32* q0       = (u32*)w;     w += (size_t)QCAP*4;         // 4 MB
  u32* q1       = (u32*)w;     w += (size_t)QCAP*4;         // 4 MB
  u32* q2       = (u32*)w;     w += (size_t)QCAP*4;         // 4 MB
  u32* cnt      = (u32*)w;     w += 256;
  (void)ws_size; (void)in_sizes; (void)n_in; (void)out_size;

  // host-side key derivation (jax.random.key(42), partitionable threefry splits)
  uint32_t ka0,ka1, sk0,sk1;
  tf2x32(0u,42u, 0u,0u, ka0,ka1);
  tf2x32(0u,42u, 0u,1u, sk0,sk1);
  uint32_t kb0,kb1, k10,k11, k20,k21;
  tf2x32(ka0,ka1, 0u,0u, kb0,kb1);
  tf2x32(ka0,ka1, 0u,1u, k10,k11);
  tf2x32(ka0,ka1, 0u,2u, k20,k21);
  uint32_t kc0,kc1, kf0,kf1;
  tf2x32(kb0,kb1, 0u,0u, kc0,kc1);
  tf2x32(kb0,kb1, 0u,1u, kf0,kf1);

  hipMemsetAsync(cnt, 0, 3*sizeof(u32), stream);

  // 0) preps
  kcvt<<<(NH*NV+255)/256, 256, 0, stream>>>(W, W64, NH*NV);
  kcvt<<<(NH*NH+255)/256, 256, 0, stream>>>(U, U64, NH*NH);
  kprepU<<<(NH*NH/4)/256, 256, 0, stream>>>(U, UB);
  kprepA<<<(NH*NV)/256, 256, 0, stream>>>(W, A1, A2);
  kprepAW<<<(NH*NV)/256, 256, 0, stream>>>(W, AW1, AW2);
  kprepAU<<<(NH*NH)/256, 256, 0, stream>>>(U, AU1, AU2);
  kpack_f32<<<TBsz/256, 256, 0, stream>>>(vd, vdbits);

  // 1) WvT = (W @ v_data)^T  (f64, [t][b][h])
  kWv<<<TT*(NH/8), 256, 0, stream>>>(vdbits, W64, WvT);

  // 2) fused mean-field recurrence
  krecur<<<BB, NH, 0, stream>>>(WvT, UB, bh, binit, rT);

  // 2b) out_r transpose + h1 = bernoulli(sk, r) fused
  ktrans_s<<<dim3(TT, NH/32, BB/32), 256, 0, stream>>>(rT, out_r,
                                                       (uint8_t*)h1bits, sk0, sk1);

  // 3) v1 = bernoulli(k1, sigmoid(W^T h1 + bv)) : bf16-MFMA fast + f64 fix
  kvisM<<<16*512, 256, 0, stream>>>(A1, A2, bv, h1bits, v1bits, nullptr,
                                    q0, cnt+0, k10, k11);
  kvis_fix<<<128, 256, 0, stream>>>(W, bv, h1bits, v1bits, nullptr,
                                    q0, cnt+0, k10, k11);

  // 4) h2 = bernoulli(k2, sigmoid(W v1 + U r_lag + bias)) : bf16-MFMA + f64 fix
  khidM<<<8*512, 256, 0, stream>>>(AW1, AW2, AU1, AU2, bh, binit,
                                   v1bits, out_r, h2bits, q1, cnt+1, k20, k21);
  khid_fix<<<128, 256, 0, stream>>>(v1bits, W, U64, bh, binit, rT,
                                    h2bits, q1, cnt+1, k20, k21);

  // 5) v_model = bernoulli(kf, sigmoid(W^T h2 + bv)) -> out_v
  kvisM<<<16*512, 256, 0, stream>>>(A1, A2, bv, h2bits, nullptr, out_v,
                                    q2, cnt+2, kf0, kf1);
  kvis_fix<<<128, 256, 0, stream>>>(W, bv, h2bits, nullptr, out_v,
                                    q2, cnt+2, kf0, kf1);
}